// Round 6
// baseline (1462.697 us; speedup 1.0000x reference)
//
#include <hip/hip_runtime.h>
#include <hip/hip_fp16.h>
#include <stdint.h>

#define BB 8
#define NN 4096
#define ATTRD 16
#define HD 64
#define STEPS 8
#define NODES (BB*NN)      // 32768
#define KPAD 196           // xs row stride in floats (gate-proven)
#define CHUNK 256          // srcs staged per LDS tile
#define NCHUNK (NN/CHUNK)  // 16

typedef _Float16 half8 __attribute__((ext_vector_type(8)));
typedef float floatx4 __attribute__((ext_vector_type(4)));
typedef unsigned long long ull;
typedef unsigned int u32;

// byte (8 adjacency bits) -> half8 of 0.0/1.0
__device__ __forceinline__ half8 expand01(u32 b) {
    union { u32 u[4]; half8 h; } r;
    r.u[0] = ((b & 1u)   ? 0x3C00u : 0u) | ((b & 2u)   ? 0x3C000000u : 0u);
    r.u[1] = ((b & 4u)   ? 0x3C00u : 0u) | ((b & 8u)   ? 0x3C000000u : 0u);
    r.u[2] = ((b & 16u)  ? 0x3C00u : 0u) | ((b & 32u)  ? 0x3C000000u : 0u);
    r.u[3] = ((b & 64u)  ? 0x3C00u : 0u) | ((b & 128u) ? 0x3C000000u : 0u);
    return r.h;
}

// ---------------- init: h = relu(attr @ Wi^T + bi); fp32 master + TRANSPOSED fp16 [batch][ch][node] ----
__global__ __launch_bounds__(256) void init_h_kernel(const float* __restrict__ attr,
                                                     const float* __restrict__ Wi,
                                                     const float* __restrict__ bi,
                                                     float* __restrict__ h,
                                                     _Float16* __restrict__ h16T) {
    __shared__ float hl[64][65];
    int bid = blockIdx.x, tid = threadIdx.x;
    int nodeg0 = bid * 64;                           // 64 nodes per block
    int nl = tid >> 2, cq = tid & 3;
    const float* a = attr + (size_t)(nodeg0 + nl) * ATTRD;
#pragma unroll
    for (int cc = 0; cc < 16; cc++) {
        int c = cq * 16 + cc;
        const float* w = Wi + c * ATTRD;
        float acc = bi[c];
#pragma unroll
        for (int k = 0; k < ATTRD; k++) acc += a[k] * w[k];
        hl[nl][c] = acc > 0.f ? acc : 0.f;
    }
    __syncthreads();
#pragma unroll
    for (int i = 0; i < 16; i++) {                   // fp32 master, coalesced
        int idx = tid + i * 256;
        h[(size_t)nodeg0 * 64 + idx] = hl[idx >> 6][idx & 63];
    }
    {                                                // transposed fp16 mirror
        int ch = tid & 63, seg = tid >> 6;
        int batch = nodeg0 >> 12;
        int nloc = (nodeg0 & 4095) + seg * 16;
        union { ushort us[16]; uint4 u4[2]; } pk;
#pragma unroll
        for (int k = 0; k < 16; k++) {
            __half hv = __float2half(hl[seg * 16 + k][ch]);
            pk.us[k] = *(ushort*)&hv;
        }
        uint4* dst = (uint4*)(h16T + (size_t)batch * 64 * NN + (size_t)ch * NN + nloc);
        dst[0] = pk.u4[0];
        dst[1] = pk.u4[1];
    }
}

// ---------------- weight prep: split-fp16 MFMA B-fragments (r8-proven, unchanged) ----------------
__global__ void wprep_kernel(const float* __restrict__ Wz, const float* __restrict__ Wr,
                             const float* __restrict__ Wh,
                             _Float16* __restrict__ wf_hi, _Float16* __restrict__ wf_lo) {
    int t = blockIdx.x * blockDim.x + threadIdx.x;
    if (t >= 3 * 4 * 6 * 64 * 8) return;
    int mat = t / 12288, rem = t % 12288;
    int tile = rem / 3072, rem2 = rem % 3072;
    int kc = rem2 / 512, rem3 = rem2 % 512;
    int lane = rem3 / 8, j = rem3 % 8;
    int k = kc * 32 + (lane >> 4) * 8 + j;
    int och = tile * 16 + (lane & 15);
    const float* W = (mat == 0) ? Wz : (mat == 1) ? Wr : Wh;
    float v = W[och * 192 + k];
    _Float16 hi = (_Float16)v;
    wf_hi[t] = hi;
    wf_lo[t] = (_Float16)(v - (float)hi);
}

// ---------------- adjacency -> bitmasks: bm[row][64 words over cols], bmT[col][64 words over rows] ----
__global__ __launch_bounds__(256) void adj_bitmask_kernel(const float4* __restrict__ A4,
                                                          ull* __restrict__ bm,
                                                          ull* __restrict__ bmT) {
    __shared__ unsigned char nibs[4][16][64];
    int wave = threadIdx.x >> 6, l = threadIdx.x & 63;
    int row = blockIdx.x * 4 + wave;                 // global row 0..32767
    int rowl = row & 4095;
    int colbase = row & ~4095;                       // batch*4096
    const float4* rp = A4 + (size_t)row * 1024;
    float4 v[16];
#pragma unroll
    for (int t = 0; t < 16; t++) v[t] = rp[t * 64 + l];   // 16 coalesced 1KB loads in flight
#pragma unroll
    for (int t = 0; t < 16; t++) {
        float4 vv = v[t];
        unsigned nib = (vv.x != 0.f ? 1u : 0u) | (vv.y != 0.f ? 2u : 0u) |
                       (vv.z != 0.f ? 4u : 0u) | (vv.w != 0.f ? 8u : 0u);
        nibs[wave][t][l] = (unsigned char)nib;
        if (nib) {                                   // transposed bits via atomicOr (~41/row)
            int cb = 4 * (t * 64 + l);
            float q0 = vv.x, q1 = vv.y, q2 = vv.z, q3 = vv.w;
            ull bit = 1ull << (rowl & 63);
            int wofs = rowl >> 6;
            if (q0 != 0.f) atomicOr(&bmT[(size_t)(colbase + cb + 0) * 64 + wofs], bit);
            if (q1 != 0.f) atomicOr(&bmT[(size_t)(colbase + cb + 1) * 64 + wofs], bit);
            if (q2 != 0.f) atomicOr(&bmT[(size_t)(colbase + cb + 2) * 64 + wofs], bit);
            if (q3 != 0.f) atomicOr(&bmT[(size_t)(colbase + cb + 3) * 64 + wofs], bit);
        }
    }
    __syncthreads();
    // assemble row-major words: thread -> (row r of block, word W); col = 64W + 4k + q <-> nib bit q
    int r = threadIdx.x >> 6, W = threadIdx.x & 63;
    int t = W >> 2, sub = W & 3;
    ull wd = 0;
#pragma unroll
    for (int k = 0; k < 16; k++)
        wd |= (ull)nibs[r][t][sub * 16 + k] << (4 * k);
    bm[(size_t)(blockIdx.x * 4 + r) * 64 + W] = wd;
}

// ---------------- fused step: dense bitmask-MFMA aggregation + per-wave gate MFMA ----------------
// Block = 64 out-nodes (512 blocks). Wave w owns 16 nodes. Aggregation: for each 256-src chunk,
// stage hT[64ch][256src] (XOR-swizzled) in LDS; A-frags expanded from bm/bmT bytes (shared B-frags
// across both directions); D[node][ch] accumulates in fp32. Gate: r8-proven split-fp16 math,
// per-wave (no barriers). h16T double-buffered across steps.
__global__ __launch_bounds__(256) void step_kernel(
        const _Float16* __restrict__ hTin, const ull* __restrict__ bm, const ull* __restrict__ bmT,
        const _Float16* __restrict__ wf_hi, const _Float16* __restrict__ wf_lo,
        const float* __restrict__ bz, const float* __restrict__ br, const float* __restrict__ bh,
        float* __restrict__ h, _Float16* __restrict__ hTout) {
    __shared__ __attribute__((aligned(16))) float xs[64][KPAD];   // 50.2 KB; first 32 KB doubles as hT stage
    char* smem = (char*)&xs[0][0];
    int bid = blockIdx.x;
    int batch = bid >> 6, tile = bid & 63;
    int tid = threadIdx.x;
    int w = tid >> 6, l = tid & 63;
    int rl = l & 15, kg = l >> 4;
    int nb = tile * 64;
    const _Float16* hin = hTin + (size_t)batch * 64 * NN;
    int growbase = batch * 4096 + nb + w * 16 + rl;             // this lane's bm row
    const uint2* bmrow  = (const uint2*)(bm  + (size_t)growbase * 64);
    const uint2* bmTrow = (const uint2*)(bmT + (size_t)growbase * 64);

    floatx4 accI[4], accO[4];
#pragma unroll
    for (int ct = 0; ct < 4; ct++) { accI[ct] = {0.f,0.f,0.f,0.f}; accO[ct] = {0.f,0.f,0.f,0.f}; }

    for (int c = 0; c < NCHUNK; ++c) {
        if (c) __syncthreads();                                 // prev chunk consumed
        {   // stage hT chunk: thread -> (ch = tid>>2, 128B segment)
            int ch = tid >> 2, part = tid & 3;
            const uint4* gsrc = (const uint4*)(hin + (size_t)ch * NN + c * CHUNK + part * 64);
#pragma unroll
            for (int u = 0; u < 8; u++) {
                uint4 d = gsrc[u];
                int s = part * 64 + u * 8;
                int bo = (ch * (CHUNK * 2) + s * 2) ^ ((ch & 7) << 4);
                *(uint4*)(smem + bo) = d;
            }
        }
        __syncthreads();
        uint2 wA = bmrow[c * 4 + kg];                           // this lane-group's word
        uint2 wB = bmTrow[c * 4 + kg];
#pragma unroll
        for (int kc = 0; kc < 8; ++kc) {
            u32 sA = (kc & 1) ? wA.y : wA.x;
            u32 sB = (kc & 1) ? wB.y : wB.x;
            int srcl = rl + ((kc >> 1) << 4);                   // lane holding needed word
            u32 bA = ((u32)__shfl((int)sA, srcl) >> (kg * 8)) & 255u;
            u32 bB = ((u32)__shfl((int)sB, srcl) >> (kg * 8)) & 255u;
            half8 aI = expand01(bA);
            half8 aO = expand01(bB);
#pragma unroll
            for (int ct = 0; ct < 4; ++ct) {
                int ch = ct * 16 + rl;
                int bo = (ch * (CHUNK * 2) + (kc * 32 + kg * 8) * 2) ^ ((ch & 7) << 4);
                half8 bf = *(const half8*)(smem + bo);          // B-frag shared by both dirs
                accI[ct] = __builtin_amdgcn_mfma_f32_16x16x32_f16(aI, bf, accI[ct], 0, 0, 0);
                accO[ct] = __builtin_amdgcn_mfma_f32_16x16x32_f16(aO, bf, accO[ct], 0, 0, 0);
            }
        }
    }
    __syncthreads();                                            // stage region becomes xs

    // ---------- write aggregation -> xs rows (own wave's 16 nodes) + fp32 h slot ----------
#pragma unroll
    for (int ct = 0; ct < 4; ++ct)
#pragma unroll
        for (int rg = 0; rg < 4; ++rg) {
            int rowi = w * 16 + kg * 4 + rg;                    // D row=(lane>>4)*4+rg
            xs[rowi][ct * 16 + rl]      = accI[ct][rg];
            xs[rowi][64 + ct * 16 + rl] = accO[ct][rg];
        }
    {
        int gnode0 = batch * 4096 + nb + w * 16;
#pragma unroll
        for (int r = 0; r < 16; r++)
            xs[w * 16 + r][128 + l] = h[(size_t)(gnode0 + r) * 64 + l];
    }

    // ---------- gate: per-wave split-fp16 MFMA over own 16 nodes, all 64 ch ----------
    const half8* WH = (const half8*)wf_hi;
    const half8* WL = (const half8*)wf_lo;
    int m = rl, q = kg;
    int r0 = w * 16;
    floatx4 accz[4], accr[4];
#pragma unroll
    for (int ct = 0; ct < 4; ct++) { accz[ct] = {0.f,0.f,0.f,0.f}; accr[ct] = {0.f,0.f,0.f,0.f}; }
#pragma unroll
    for (int kc = 0; kc < 6; kc++) {
        const float* xr = &xs[r0 + m][kc * 32 + q * 8];
        float4 xa = *(const float4*)xr;
        float4 xb = *(const float4*)(xr + 4);
        float xv[8] = {xa.x, xa.y, xa.z, xa.w, xb.x, xb.y, xb.z, xb.w};
        half8 ahi, alo;
#pragma unroll
        for (int j = 0; j < 8; j++) {
            _Float16 hj = (_Float16)xv[j];
            ahi[j] = hj;
            alo[j] = (_Float16)(xv[j] - (float)hj);
        }
#pragma unroll
        for (int ct = 0; ct < 4; ct++) {
            half8 bzh = WH[((0 * 4 + ct) * 6 + kc) * 64 + l];
            half8 bzl = WL[((0 * 4 + ct) * 6 + kc) * 64 + l];
            half8 brh = WH[((1 * 4 + ct) * 6 + kc) * 64 + l];
            half8 brl = WL[((1 * 4 + ct) * 6 + kc) * 64 + l];
            accz[ct] = __builtin_amdgcn_mfma_f32_16x16x32_f16(ahi, bzh, accz[ct], 0, 0, 0);
            accz[ct] = __builtin_amdgcn_mfma_f32_16x16x32_f16(alo, bzh, accz[ct], 0, 0, 0);
            accz[ct] = __builtin_amdgcn_mfma_f32_16x16x32_f16(ahi, bzl, accz[ct], 0, 0, 0);
            accr[ct] = __builtin_amdgcn_mfma_f32_16x16x32_f16(ahi, brh, accr[ct], 0, 0, 0);
            accr[ct] = __builtin_amdgcn_mfma_f32_16x16x32_f16(alo, brh, accr[ct], 0, 0, 0);
            accr[ct] = __builtin_amdgcn_mfma_f32_16x16x32_f16(ahi, brl, accr[ct], 0, 0, 0);
        }
    }
    float zreg[4][4], hvreg[4][4];
#pragma unroll
    for (int ct = 0; ct < 4; ct++) {
        float bzv = bz[ct * 16 + rl], brv = br[ct * 16 + rl];
#pragma unroll
        for (int rg = 0; rg < 4; rg++) {
            float z  = 1.f / (1.f + __expf(-(accz[ct][rg] + bzv)));
            float rr = 1.f / (1.f + __expf(-(accr[ct][rg] + brv)));
            float hv = xs[r0 + q * 4 + rg][128 + ct * 16 + rl];
            zreg[ct][rg] = z; hvreg[ct][rg] = hv;
            xs[r0 + q * 4 + rg][128 + ct * 16 + rl] = rr * hv;  // same lane reads then writes this slot
        }
    }
    floatx4 acch[4];
#pragma unroll
    for (int ct = 0; ct < 4; ct++) acch[ct] = {0.f,0.f,0.f,0.f};
#pragma unroll
    for (int kc = 0; kc < 6; kc++) {
        const float* xr = &xs[r0 + m][kc * 32 + q * 8];
        float4 xa = *(const float4*)xr;
        float4 xb = *(const float4*)(xr + 4);
        float xv[8] = {xa.x, xa.y, xa.z, xa.w, xb.x, xb.y, xb.z, xb.w};
        half8 ahi, alo;
#pragma unroll
        for (int j = 0; j < 8; j++) {
            _Float16 hj = (_Float16)xv[j];
            ahi[j] = hj;
            alo[j] = (_Float16)(xv[j] - (float)hj);
        }
#pragma unroll
        for (int ct = 0; ct < 4; ct++) {
            half8 bhh = WH[((2 * 4 + ct) * 6 + kc) * 64 + l];
            half8 bhl = WL[((2 * 4 + ct) * 6 + kc) * 64 + l];
            acch[ct] = __builtin_amdgcn_mfma_f32_16x16x32_f16(ahi, bhh, acch[ct], 0, 0, 0);
            acch[ct] = __builtin_amdgcn_mfma_f32_16x16x32_f16(alo, bhh, acch[ct], 0, 0, 0);
            acch[ct] = __builtin_amdgcn_mfma_f32_16x16x32_f16(ahi, bhl, acch[ct], 0, 0, 0);
        }
    }
#pragma unroll
    for (int ct = 0; ct < 4; ct++) {
        float bhv = bh[ct * 16 + rl];
#pragma unroll
        for (int rg = 0; rg < 4; rg++) {
            float pre = acch[ct][rg] + bhv;
            float th = 2.f / (1.f + __expf(-2.f * pre)) - 1.f;
            float hv = hvreg[ct][rg];
            xs[r0 + q * 4 + rg][ct * 16 + rl] = hv + zreg[ct][rg] * (th - hv);  // stage h'
        }
    }
    {   // fp32 h write (own rows, coalesced)
        int gnode0 = batch * 4096 + nb + w * 16;
#pragma unroll
        for (int r = 0; r < 16; r++)
            h[(size_t)(gnode0 + r) * 64 + l] = xs[r0 + r][l];
    }
    __syncthreads();
    {   // transposed fp16 epilogue (block-coalesced 32B chunks)
        int ch = tid & 63, seg = tid >> 6;
        union { ushort us[16]; uint4 u4[2]; } pk;
#pragma unroll
        for (int k = 0; k < 16; k++) {
            __half hv = __float2half(xs[seg * 16 + k][ch]);
            pk.us[k] = *(ushort*)&hv;
        }
        uint4* dst = (uint4*)(hTout + (size_t)batch * 64 * NN + (size_t)ch * NN + nb + seg * 16);
        dst[0] = pk.u4[0];
        dst[1] = pk.u4[1];
    }
}

// ---------------- output: out = h @ Wo^T + bo ----------------
__global__ void out_kernel(const float* __restrict__ h, const float* __restrict__ Wo,
                           const float* __restrict__ bo, float* __restrict__ out) {
    int wid = (blockIdx.x * blockDim.x + threadIdx.x) >> 6;
    int l = threadIdx.x & 63;
    if (wid >= NODES) return;
    float p = h[(wid << 6) | l] * Wo[l];
#pragma unroll
    for (int off = 32; off > 0; off >>= 1) p += __shfl_down(p, off);
    if (l == 0) out[wid] = p + bo[0];
}

extern "C" void kernel_launch(void* const* d_in, const int* in_sizes, int n_in,
                              void* d_out, int out_size, void* d_ws, size_t ws_size,
                              hipStream_t stream) {
    const float* attr = (const float*)d_in[0];
    const float* adj  = (const float*)d_in[1];
    const float* Wi   = (const float*)d_in[2];
    const float* bi   = (const float*)d_in[3];
    const float* Wz   = (const float*)d_in[4];
    const float* bz   = (const float*)d_in[5];
    const float* Wr   = (const float*)d_in[6];
    const float* br   = (const float*)d_in[7];
    const float* Wh   = (const float*)d_in[8];
    const float* bh   = (const float*)d_in[9];
    const float* Wo   = (const float*)d_in[10];
    const float* bo   = (const float*)d_in[11];
    float* out = (float*)d_out;

    char* ws = (char*)d_ws;
    size_t off = 0;
    auto carve = [&](size_t bytes) { void* p = ws + off; off = (off + bytes + 255) & ~(size_t)255; return p; };
    float* h        = (float*)carve((size_t)NODES * HD * 4);          // 8.4 MB
    _Float16* hTa   = (_Float16*)carve((size_t)NODES * HD * 2);       // 4.2 MB transposed [b][ch][n]
    _Float16* hTb   = (_Float16*)carve((size_t)NODES * HD * 2);       // 4.2 MB
    _Float16* wf_hi = (_Float16*)carve(3 * 4 * 6 * 64 * 8 * 2);       // 73.7 KB
    _Float16* wf_lo = (_Float16*)carve(3 * 4 * 6 * 64 * 8 * 2);       // 73.7 KB
    ull* bm         = (ull*)carve((size_t)NODES * 64 * 8);            // 16.8 MB row bitmask
    ull* bmT        = (ull*)carve((size_t)NODES * 64 * 8);            // 16.8 MB col bitmask

    hipMemsetAsync(bmT, 0, (size_t)NODES * 64 * 8, stream);           // bm fully written, no memset

    init_h_kernel<<<NODES / 64, 256, 0, stream>>>(attr, Wi, bi, h, hTa);
    wprep_kernel<<<(3 * 4 * 6 * 64 * 8 + 255) / 256, 256, 0, stream>>>(Wz, Wr, Wh, wf_hi, wf_lo);
    adj_bitmask_kernel<<<NODES / 4, 256, 0, stream>>>((const float4*)adj, bm, bmT);

    for (int step = 0; step < STEPS; ++step) {
        const _Float16* hin = (step & 1) ? hTb : hTa;
        _Float16* hout      = (step & 1) ? hTa : hTb;
        step_kernel<<<NODES / 64, 256, 0, stream>>>(
            hin, bm, bmT, wf_hi, wf_lo, bz, br, bh, h, hout);
    }
    out_kernel<<<NODES * HD / 256, 256, 0, stream>>>(h, Wo, bo, out);
}